// Round 1
// baseline (1128.142 us; speedup 1.0000x reference)
//
#include <hip/hip_runtime.h>
#include <stdint.h>

typedef __bf16 bf16x8 __attribute__((ext_vector_type(8)));
typedef float f32x4 __attribute__((ext_vector_type(4)));

__device__ __forceinline__ unsigned short f2b(float f) {
  unsigned int u = __builtin_bit_cast(unsigned int, f);
  u += 0x7fffu + ((u >> 16) & 1u);
  return (unsigned short)(u >> 16);
}
__device__ __forceinline__ float b2f(unsigned short h) {
  unsigned int u = ((unsigned int)h) << 16;
  return __builtin_bit_cast(float, u);
}
__device__ __forceinline__ unsigned short to_bits(float f) { return f2b(f); }
__device__ __forceinline__ unsigned short to_bits(unsigned short u) { return u; }

// ---------------------------------------------------------------------------
// NT GEMM: C[M,N] = scale * (A @ BT^T) + bias.  A:[M,K] bf16 row-major,
// BT:[N,K] bf16 row-major (i.e. B transposed). 128x128 tile, BK=32, 4 waves.
// ---------------------------------------------------------------------------
template <int OUT_BF16, int HAS_BIAS>
__global__ __launch_bounds__(256, 2) void gemm_bt(
    const unsigned short* __restrict__ A, const unsigned short* __restrict__ BT,
    const float* __restrict__ bias, void* __restrict__ Cv, int M, int N, int K,
    float scale) {
  __shared__ __align__(16) unsigned short sA[128 * 32];
  __shared__ __align__(16) unsigned short sB[128 * 32];

  const int t = threadIdx.x;
  const int lane = t & 63;
  const int wave = t >> 6;
  const int wr = (wave >> 1) * 64;  // wave row offset in tile
  const int wc = (wave & 1) * 64;   // wave col offset in tile
  const long tileM = (long)blockIdx.y * 128;
  const long tileN = (long)blockIdx.x * 128;

  // staging coords: each thread copies 8 bf16 (16B) per row-half
  const int sr = t >> 2;         // 0..63
  const int sk = (t & 3) * 8;    // k element offset
  const unsigned short* Ap = A + (tileM + sr) * K + sk;
  const unsigned short* Bp = BT + (tileN + sr) * K + sk;
  const long rowstep = (long)64 * K;

  f32x4 acc[4][4];
#pragma unroll
  for (int m = 0; m < 4; ++m)
#pragma unroll
    for (int n = 0; n < 4; ++n) acc[m][n] = (f32x4)(0.f);

  const int fr = lane & 15;        // fragment row
  const int fk = (lane >> 4) * 8;  // fragment k offset

  for (int k0 = 0; k0 < K; k0 += 32) {
    *(uint4*)(&sA[sr * 32 + sk]) = *(const uint4*)(Ap + k0);
    *(uint4*)(&sA[(sr + 64) * 32 + sk]) = *(const uint4*)(Ap + rowstep + k0);
    *(uint4*)(&sB[sr * 32 + sk]) = *(const uint4*)(Bp + k0);
    *(uint4*)(&sB[(sr + 64) * 32 + sk]) = *(const uint4*)(Bp + rowstep + k0);
    __syncthreads();

    bf16x8 fa[4], fb[4];
#pragma unroll
    for (int m = 0; m < 4; ++m)
      fa[m] = *(const bf16x8*)(&sA[(wr + m * 16 + fr) * 32 + fk]);
#pragma unroll
    for (int n = 0; n < 4; ++n)
      fb[n] = *(const bf16x8*)(&sB[(wc + n * 16 + fr) * 32 + fk]);
#pragma unroll
    for (int m = 0; m < 4; ++m)
#pragma unroll
      for (int n = 0; n < 4; ++n)
        acc[m][n] = __builtin_amdgcn_mfma_f32_16x16x32_bf16(fa[m], fb[n],
                                                            acc[m][n], 0, 0, 0);
    __syncthreads();
  }

  // C/D layout (m89-verified): col = lane&15, row = (lane>>4)*4 + j
  const int cr = (lane >> 4) * 4;
  const int cc = lane & 15;
#pragma unroll
  for (int m = 0; m < 4; ++m) {
#pragma unroll
    for (int n = 0; n < 4; ++n) {
      const long col = tileN + wc + n * 16 + cc;
      const float bv = HAS_BIAS ? bias[col] : 0.f;
#pragma unroll
      for (int j = 0; j < 4; ++j) {
        const long row = tileM + wr + m * 16 + cr + j;
        float v = acc[m][n][j] * scale + bv;
        if (OUT_BF16)
          ((unsigned short*)Cv)[row * N + col] = f2b(v);
        else
          ((float*)Cv)[row * N + col] = v;
      }
    }
  }
}

// ---------------------------------------------------------------------------
// Row softmax over bf16 rows of length 4096, in place. One block per row.
// ---------------------------------------------------------------------------
__global__ __launch_bounds__(256) void softmax_rows(unsigned short* S,
                                                    int ncols) {
  const int t = threadIdx.x;
  const int lane = t & 63;
  const int wave = t >> 6;
  unsigned short* p = S + (long)blockIdx.x * ncols + t * 16;
  uint4 d0 = *(const uint4*)(p);
  uint4 d1 = *(const uint4*)(p + 8);
  unsigned int w[8] = {d0.x, d0.y, d0.z, d0.w, d1.x, d1.y, d1.z, d1.w};
  float v[16];
#pragma unroll
  for (int i = 0; i < 8; ++i) {
    v[2 * i] = b2f((unsigned short)(w[i] & 0xffffu));
    v[2 * i + 1] = b2f((unsigned short)(w[i] >> 16));
  }
  float mx = v[0];
#pragma unroll
  for (int i = 1; i < 16; ++i) mx = fmaxf(mx, v[i]);
#pragma unroll
  for (int off = 32; off > 0; off >>= 1) mx = fmaxf(mx, __shfl_xor(mx, off, 64));
  __shared__ float redm[4], reds[4];
  if (lane == 0) redm[wave] = mx;
  __syncthreads();
  mx = fmaxf(fmaxf(redm[0], redm[1]), fmaxf(redm[2], redm[3]));
  float sum = 0.f;
#pragma unroll
  for (int i = 0; i < 16; ++i) {
    v[i] = __expf(v[i] - mx);
    sum += v[i];
  }
#pragma unroll
  for (int off = 32; off > 0; off >>= 1) sum += __shfl_xor(sum, off, 64);
  if (lane == 0) reds[wave] = sum;
  __syncthreads();
  const float inv = 1.f / (reds[0] + reds[1] + reds[2] + reds[3]);
  unsigned int o[8];
#pragma unroll
  for (int i = 0; i < 8; ++i)
    o[i] = (unsigned int)f2b(v[2 * i] * inv) |
           ((unsigned int)f2b(v[2 * i + 1] * inv) << 16);
  *(uint4*)(p) = make_uint4(o[0], o[1], o[2], o[3]);
  *(uint4*)(p + 8) = make_uint4(o[4], o[5], o[6], o[7]);
}

// ---------------------------------------------------------------------------
// Tiled transpose (+cast to bf16): out[C][R] = in[R][C]. block (32,8), z=batch.
// ---------------------------------------------------------------------------
template <typename TIN>
__global__ void transpose_cast(const TIN* __restrict__ in,
                               unsigned short* __restrict__ out, int R, int C) {
  __shared__ unsigned short tile[32][33];
  const long zoff = (long)blockIdx.z * R * C;
  in += zoff;
  out += zoff;
  const int tx = threadIdx.x, ty = threadIdx.y;
  const int bx = blockIdx.x * 32;  // col base
  const int by = blockIdx.y * 32;  // row base
#pragma unroll
  for (int i = 0; i < 4; ++i)
    tile[ty + i * 8][tx] = to_bits(in[(long)(by + ty + i * 8) * C + bx + tx]);
  __syncthreads();
#pragma unroll
  for (int i = 0; i < 4; ++i)
    out[(long)(bx + ty + i * 8) * R + by + tx] = tile[tx][ty + i * 8];
}

// ---------------------------------------------------------------------------
// Elementwise fp32 -> bf16 cast, vectorized float4 -> 4x bf16.
// ---------------------------------------------------------------------------
__global__ __launch_bounds__(256) void cast_f32_bf16(
    const float* __restrict__ in, unsigned short* __restrict__ out, long n) {
  long i = ((long)blockIdx.x * 256 + threadIdx.x) * 4;
  const long stride = (long)gridDim.x * 256 * 4;
  for (; i < n; i += stride) {
    float4 f = *(const float4*)(&in[i]);
    uint2 o;
    o.x = (unsigned int)f2b(f.x) | ((unsigned int)f2b(f.y) << 16);
    o.y = (unsigned int)f2b(f.z) | ((unsigned int)f2b(f.w) << 16);
    *(uint2*)(&out[i]) = o;
  }
}

extern "C" void kernel_launch(void* const* d_in, const int* in_sizes, int n_in,
                              void* d_out, int out_size, void* d_ws,
                              size_t ws_size, hipStream_t stream) {
  constexpr int Bb = 4, S = 4096, D = 1024;
  constexpr long SD = (long)S * D;
  const float* query = (const float*)d_in[0];
  const float* key_ = (const float*)d_in[1];
  const float* value = (const float*)d_in[2];
  const float* Wh = (const float*)d_in[3];
  const float* bh = (const float*)d_in[4];
  const float* Wk = (const float*)d_in[5];
  const float* bk = (const float*)d_in[6];
  const float* Wv = (const float*)d_in[7];
  const float* bv = (const float*)d_in[8];
  const float* Wo = (const float*)d_in[9];
  const float* bo = (const float*)d_in[10];
  float* out = (float*)d_out;

  char* ws = (char*)d_ws;
  const long MB = 1024 * 1024;
  if (ws_size < (size_t)(232 * MB)) return;  // loud failure: out stays zero
  unsigned short* whT = (unsigned short*)(ws + 0 * MB);
  unsigned short* wkT = (unsigned short*)(ws + 2 * MB);
  unsigned short* wvT = (unsigned short*)(ws + 4 * MB);
  unsigned short* woT = (unsigned short*)(ws + 6 * MB);
  unsigned short* Xb = (unsigned short*)(ws + 8 * MB);    // cast input (32MB)
  unsigned short* q = (unsigned short*)(ws + 40 * MB);    // q proj (32MB)
  unsigned short* Kb = (unsigned short*)(ws + 72 * MB);   // k proj (32MB)
  unsigned short* Vb = (unsigned short*)(ws + 104 * MB);  // v / attn_out (32MB)
  unsigned short* VT = (unsigned short*)(ws + 136 * MB);  // v transposed (32MB)
  unsigned short* Hb = (unsigned short*)(ws + 168 * MB);  // hidden (32MB)
  unsigned short* Sc = (unsigned short*)(ws + 200 * MB);  // scores (32MB)

  dim3 tb32(32, 8);
  transpose_cast<float><<<dim3(32, 32, 1), tb32, 0, stream>>>(Wh, whT, D, D);
  transpose_cast<float><<<dim3(32, 32, 1), tb32, 0, stream>>>(Wk, wkT, D, D);
  transpose_cast<float><<<dim3(32, 32, 1), tb32, 0, stream>>>(Wv, wvT, D, D);
  transpose_cast<float><<<dim3(32, 32, 1), tb32, 0, stream>>>(Wo, woT, D, D);

  const long nX = (long)Bb * SD;
  dim3 gProj(D / 128, Bb * S / 128);  // (8, 128)

  // q = bf16(query) @ Wh + bh
  cast_f32_bf16<<<2048, 256, 0, stream>>>(query, Xb, nX);
  gemm_bt<1, 1><<<gProj, 256, 0, stream>>>(Xb, whT, bh, q, Bb * S, D, D, 1.f);
  // k = (key @ Wh + bh) @ Wk + bk
  cast_f32_bf16<<<2048, 256, 0, stream>>>(key_, Xb, nX);
  gemm_bt<1, 1><<<gProj, 256, 0, stream>>>(Xb, whT, bh, Hb, Bb * S, D, D, 1.f);
  gemm_bt<1, 1><<<gProj, 256, 0, stream>>>(Hb, wkT, bk, Kb, Bb * S, D, D, 1.f);
  // v = (value @ Wh + bh) @ Wv + bv
  cast_f32_bf16<<<2048, 256, 0, stream>>>(value, Xb, nX);
  gemm_bt<1, 1><<<gProj, 256, 0, stream>>>(Xb, whT, bh, Hb, Bb * S, D, D, 1.f);
  gemm_bt<1, 1><<<gProj, 256, 0, stream>>>(Hb, wvT, bv, Vb, Bb * S, D, D, 1.f);

  // VT[b] = v[b]^T  ([D][S])
  transpose_cast<unsigned short>
      <<<dim3(D / 32, S / 32, Bb), tb32, 0, stream>>>(Vb, VT, S, D);

  for (int b = 0; b < Bb; ++b) {
    const unsigned short* qb = q + b * SD;
    const unsigned short* kb = Kb + b * SD;
    const unsigned short* vtb = VT + b * SD;
    unsigned short* ob = Vb + b * SD;  // v no longer needed -> attn_out
    // scores = q @ k^T / 1024
    gemm_bt<1, 0><<<dim3(S / 128, S / 128), 256, 0, stream>>>(
        qb, kb, nullptr, Sc, S, S, D, 1.f / 1024.f);
    softmax_rows<<<S, 256, 0, stream>>>(Sc, S);
    // attn_out = attn @ v   (B^T = VT)
    gemm_bt<1, 0><<<dim3(D / 128, S / 128), 256, 0, stream>>>(
        Sc, vtb, nullptr, ob, S, D, S, 1.f);
  }

  // out = attn_out @ Wo + bo  (fp32 output)
  gemm_bt<0, 1><<<gProj, 256, 0, stream>>>(Vb, woT, bo, out, Bb * S, D, D, 1.f);
}

// Round 3
// 1099.919 us; speedup vs baseline: 1.0257x; 1.0257x over previous
//
#include <hip/hip_runtime.h>
#include <stdint.h>

typedef __bf16 bf16x8 __attribute__((ext_vector_type(8)));
typedef float f32x4 __attribute__((ext_vector_type(4)));

__device__ __forceinline__ unsigned short f2b(float f) {
  unsigned int u = __builtin_bit_cast(unsigned int, f);
  u += 0x7fffu + ((u >> 16) & 1u);
  return (unsigned short)(u >> 16);
}
__device__ __forceinline__ float b2f(unsigned short h) {
  unsigned int u = ((unsigned int)h) << 16;
  return __builtin_bit_cast(float, u);
}
__device__ __forceinline__ unsigned short to_bits(float f) { return f2b(f); }
__device__ __forceinline__ unsigned short to_bits(unsigned short u) { return u; }

// async global->LDS, 16B per lane, wave-uniform LDS base (HW adds lane*16)
__device__ __forceinline__ void gl2lds16(const void* g, void* l) {
  __builtin_amdgcn_global_load_lds(
      (const __attribute__((address_space(1))) unsigned int*)g,
      (__attribute__((address_space(3))) unsigned int*)l, 16, 0, 0);
}

// ---------------------------------------------------------------------------
// NT GEMM: C[M,N] = scale * (A @ BT^T) + bias.  A:[M,K] bf16 row-major,
// BT:[N,K] bf16 row-major (i.e. B transposed). 128x128 tile, BK=32, 4 waves.
// m97 structure: global_load_lds width-16 staging, single LDS buffer.
// ---------------------------------------------------------------------------
template <int OUT_BF16, int HAS_BIAS>
__global__ __launch_bounds__(256, 2) void gemm_bt(
    const unsigned short* __restrict__ A, const unsigned short* __restrict__ BT,
    const float* __restrict__ bias, void* __restrict__ Cv, int M, int N, int K,
    float scale) {
  __shared__ __align__(16) unsigned short sA[128 * 32];
  __shared__ __align__(16) unsigned short sB[128 * 32];

  const int t = threadIdx.x;
  const int lane = t & 63;
  const int wave = t >> 6;
  const int wr = (wave >> 1) * 64;  // wave row offset in tile
  const int wc = (wave & 1) * 64;   // wave col offset in tile
  const long tileM = (long)blockIdx.y * 128;
  const long tileN = (long)blockIdx.x * 128;

  // staging coords: lane l of wave w covers tile-row 16w + (l>>2),
  // k-chunk (l&3)*8; LDS byte offset = 1024w + 16l (linear, gl2lds-compatible)
  const int sr = t >> 2;         // 0..63
  const int sk = (t & 3) * 8;    // k element offset
  const unsigned short* Ap = A + (tileM + sr) * K + sk;
  const unsigned short* Bp = BT + (tileN + sr) * K + sk;
  const long rowstep = (long)64 * K;
  unsigned short* sAw0 = &sA[wave * 512];
  unsigned short* sAw1 = &sA[2048 + wave * 512];
  unsigned short* sBw0 = &sB[wave * 512];
  unsigned short* sBw1 = &sB[2048 + wave * 512];

  f32x4 acc[4][4];
#pragma unroll
  for (int m = 0; m < 4; ++m)
#pragma unroll
    for (int n = 0; n < 4; ++n) acc[m][n] = (f32x4)(0.f);

  const int fr = lane & 15;        // fragment row
  const int fk = (lane >> 4) * 8;  // fragment k offset

  for (int k0 = 0; k0 < K; k0 += 32) {
    gl2lds16(Ap + k0, sAw0);
    gl2lds16(Ap + rowstep + k0, sAw1);
    gl2lds16(Bp + k0, sBw0);
    gl2lds16(Bp + rowstep + k0, sBw1);
    __syncthreads();  // vmcnt(0) drain + barrier

    bf16x8 fa[4], fb[4];
#pragma unroll
    for (int m = 0; m < 4; ++m)
      fa[m] = *(const bf16x8*)(&sA[(wr + m * 16 + fr) * 32 + fk]);
#pragma unroll
    for (int n = 0; n < 4; ++n)
      fb[n] = *(const bf16x8*)(&sB[(wc + n * 16 + fr) * 32 + fk]);
#pragma unroll
    for (int m = 0; m < 4; ++m)
#pragma unroll
      for (int n = 0; n < 4; ++n)
        acc[m][n] = __builtin_amdgcn_mfma_f32_16x16x32_bf16(fa[m], fb[n],
                                                            acc[m][n], 0, 0, 0);
    __syncthreads();
  }

  // C/D layout (m89-verified): col = lane&15, row = (lane>>4)*4 + j
  const int cr = (lane >> 4) * 4;
  const int cc = lane & 15;
#pragma unroll
  for (int m = 0; m < 4; ++m) {
#pragma unroll
    for (int n = 0; n < 4; ++n) {
      const long col = tileN + wc + n * 16 + cc;
      const float bv = HAS_BIAS ? bias[col] : 0.f;
#pragma unroll
      for (int j = 0; j < 4; ++j) {
        const long row = tileM + wr + m * 16 + cr + j;
        float v = acc[m][n][j] * scale + bv;
        if (OUT_BF16)
          ((unsigned short*)Cv)[row * N + col] = f2b(v);
        else
          ((float*)Cv)[row * N + col] = v;
      }
    }
  }
}

// ---------------------------------------------------------------------------
// Row softmax over bf16 rows of length 4096, in place. One block per row.
// ---------------------------------------------------------------------------
__global__ __launch_bounds__(256) void softmax_rows(unsigned short* S,
                                                    int ncols) {
  const int t = threadIdx.x;
  const int lane = t & 63;
  const int wave = t >> 6;
  unsigned short* p = S + (long)blockIdx.x * ncols + t * 16;
  uint4 d0 = *(const uint4*)(p);
  uint4 d1 = *(const uint4*)(p + 8);
  unsigned int w[8] = {d0.x, d0.y, d0.z, d0.w, d1.x, d1.y, d1.z, d1.w};
  float v[16];
#pragma unroll
  for (int i = 0; i < 8; ++i) {
    v[2 * i] = b2f((unsigned short)(w[i] & 0xffffu));
    v[2 * i + 1] = b2f((unsigned short)(w[i] >> 16));
  }
  float mx = v[0];
#pragma unroll
  for (int i = 1; i < 16; ++i) mx = fmaxf(mx, v[i]);
#pragma unroll
  for (int off = 32; off > 0; off >>= 1) mx = fmaxf(mx, __shfl_xor(mx, off, 64));
  __shared__ float redm[4], reds[4];
  if (lane == 0) redm[wave] = mx;
  __syncthreads();
  mx = fmaxf(fmaxf(redm[0], redm[1]), fmaxf(redm[2], redm[3]));
  float sum = 0.f;
#pragma unroll
  for (int i = 0; i < 16; ++i) {
    v[i] = __expf(v[i] - mx);
    sum += v[i];
  }
#pragma unroll
  for (int off = 32; off > 0; off >>= 1) sum += __shfl_xor(sum, off, 64);
  if (lane == 0) reds[wave] = sum;
  __syncthreads();
  const float inv = 1.f / (reds[0] + reds[1] + reds[2] + reds[3]);
  unsigned int o[8];
#pragma unroll
  for (int i = 0; i < 8; ++i)
    o[i] = (unsigned int)f2b(v[2 * i] * inv) |
           ((unsigned int)f2b(v[2 * i + 1] * inv) << 16);
  *(uint4*)(p) = make_uint4(o[0], o[1], o[2], o[3]);
  *(uint4*)(p + 8) = make_uint4(o[4], o[5], o[6], o[7]);
}

// ---------------------------------------------------------------------------
// Tiled transpose (+cast to bf16): out[C][R] = in[R][C]. block (32,8), z=batch.
// ---------------------------------------------------------------------------
template <typename TIN>
__global__ void transpose_cast(const TIN* __restrict__ in,
                               unsigned short* __restrict__ out, int R, int C) {
  __shared__ unsigned short tile[32][33];
  const long zoff = (long)blockIdx.z * R * C;
  in += zoff;
  out += zoff;
  const int tx = threadIdx.x, ty = threadIdx.y;
  const int bx = blockIdx.x * 32;  // col base
  const int by = blockIdx.y * 32;  // row base
#pragma unroll
  for (int i = 0; i < 4; ++i)
    tile[ty + i * 8][tx] = to_bits(in[(long)(by + ty + i * 8) * C + bx + tx]);
  __syncthreads();
#pragma unroll
  for (int i = 0; i < 4; ++i)
    out[(long)(bx + ty + i * 8) * R + by + tx] = tile[tx][ty + i * 8];
}

// ---------------------------------------------------------------------------
// Elementwise fp32 -> bf16 cast, vectorized float4 -> 4x bf16.
// ---------------------------------------------------------------------------
__global__ __launch_bounds__(256) void cast_f32_bf16(
    const float* __restrict__ in, unsigned short* __restrict__ out, long n) {
  long i = ((long)blockIdx.x * 256 + threadIdx.x) * 4;
  const long stride = (long)gridDim.x * 256 * 4;
  for (; i < n; i += stride) {
    float4 f = *(const float4*)(&in[i]);
    uint2 o;
    o.x = (unsigned int)f2b(f.x) | ((unsigned int)f2b(f.y) << 16);
    o.y = (unsigned int)f2b(f.z) | ((unsigned int)f2b(f.w) << 16);
    *(uint2*)(&out[i]) = o;
  }
}

extern "C" void kernel_launch(void* const* d_in, const int* in_sizes, int n_in,
                              void* d_out, int out_size, void* d_ws,
                              size_t ws_size, hipStream_t stream) {
  constexpr int Bb = 4, S = 4096, D = 1024;
  constexpr long SD = (long)S * D;
  const float* query = (const float*)d_in[0];
  const float* key_ = (const float*)d_in[1];
  const float* value = (const float*)d_in[2];
  const float* Wh = (const float*)d_in[3];
  const float* bh = (const float*)d_in[4];
  const float* Wk = (const float*)d_in[5];
  const float* bk = (const float*)d_in[6];
  const float* Wv = (const float*)d_in[7];
  const float* bv = (const float*)d_in[8];
  const float* Wo = (const float*)d_in[9];
  const float* bo = (const float*)d_in[10];
  float* out = (float*)d_out;

  char* ws = (char*)d_ws;
  const long MB = 1024 * 1024;
  if (ws_size < (size_t)(232 * MB)) return;  // loud failure: out stays zero
  unsigned short* whT = (unsigned short*)(ws + 0 * MB);
  unsigned short* wkT = (unsigned short*)(ws + 2 * MB);
  unsigned short* wvT = (unsigned short*)(ws + 4 * MB);
  unsigned short* woT = (unsigned short*)(ws + 6 * MB);
  unsigned short* Xb = (unsigned short*)(ws + 8 * MB);    // cast input (32MB)
  unsigned short* q = (unsigned short*)(ws + 40 * MB);    // q proj (32MB)
  unsigned short* Kb = (unsigned short*)(ws + 72 * MB);   // k proj (32MB)
  unsigned short* Vb = (unsigned short*)(ws + 104 * MB);  // v / attn_out (32MB)
  unsigned short* VT = (unsigned short*)(ws + 136 * MB);  // v transposed (32MB)
  unsigned short* Hb = (unsigned short*)(ws + 168 * MB);  // hidden (32MB)
  unsigned short* Sc = (unsigned short*)(ws + 200 * MB);  // scores (32MB)

  dim3 tb32(32, 8);
  transpose_cast<float><<<dim3(32, 32, 1), tb32, 0, stream>>>(Wh, whT, D, D);
  transpose_cast<float><<<dim3(32, 32, 1), tb32, 0, stream>>>(Wk, wkT, D, D);
  transpose_cast<float><<<dim3(32, 32, 1), tb32, 0, stream>>>(Wv, wvT, D, D);
  transpose_cast<float><<<dim3(32, 32, 1), tb32, 0, stream>>>(Wo, woT, D, D);

  const long nX = (long)Bb * SD;
  dim3 gProj(D / 128, Bb * S / 128);  // (8, 128)

  // q = bf16(query) @ Wh + bh
  cast_f32_bf16<<<2048, 256, 0, stream>>>(query, Xb, nX);
  gemm_bt<1, 1><<<gProj, 256, 0, stream>>>(Xb, whT, bh, q, Bb * S, D, D, 1.f);
  // k = (key @ Wh + bh) @ Wk + bk
  cast_f32_bf16<<<2048, 256, 0, stream>>>(key_, Xb, nX);
  gemm_bt<1, 1><<<gProj, 256, 0, stream>>>(Xb, whT, bh, Hb, Bb * S, D, D, 1.f);
  gemm_bt<1, 1><<<gProj, 256, 0, stream>>>(Hb, wkT, bk, Kb, Bb * S, D, D, 1.f);
  // v = (value @ Wh + bh) @ Wv + bv
  cast_f32_bf16<<<2048, 256, 0, stream>>>(value, Xb, nX);
  gemm_bt<1, 1><<<gProj, 256, 0, stream>>>(Xb, whT, bh, Hb, Bb * S, D, D, 1.f);
  gemm_bt<1, 1><<<gProj, 256, 0, stream>>>(Hb, wvT, bv, Vb, Bb * S, D, D, 1.f);

  // VT[b] = v[b]^T  ([D][S])
  transpose_cast<unsigned short>
      <<<dim3(D / 32, S / 32, Bb), tb32, 0, stream>>>(Vb, VT, S, D);

  for (int b = 0; b < Bb; ++b) {
    const unsigned short* qb = q + b * SD;
    const unsigned short* kb = Kb + b * SD;
    const unsigned short* vtb = VT + b * SD;
    unsigned short* ob = Vb + b * SD;  // v no longer needed -> attn_out
    // scores = q @ k^T / 1024
    gemm_bt<1, 0><<<dim3(S / 128, S / 128), 256, 0, stream>>>(
        qb, kb, nullptr, Sc, S, S, D, 1.f / 1024.f);
    softmax_rows<<<S, 256, 0, stream>>>(Sc, S);
    // attn_out = attn @ v   (B^T = VT)
    gemm_bt<1, 0><<<dim3(D / 128, S / 128), 256, 0, stream>>>(
        Sc, vtb, nullptr, ob, S, D, S, 1.f);
  }

  // out = attn_out @ Wo + bo  (fp32 output)
  gemm_bt<0, 1><<<gProj, 256, 0, stream>>>(Vb, woT, bo, out, Bb * S, D, D, 1.f);
}

// Round 4
// 1022.832 us; speedup vs baseline: 1.1030x; 1.0754x over previous
//
#include <hip/hip_runtime.h>
#include <stdint.h>

typedef __bf16 bf16x8 __attribute__((ext_vector_type(8)));
typedef float f32x4 __attribute__((ext_vector_type(4)));

__device__ __forceinline__ unsigned short f2b(float f) {
  unsigned int u = __builtin_bit_cast(unsigned int, f);
  u += 0x7fffu + ((u >> 16) & 1u);
  return (unsigned short)(u >> 16);
}
__device__ __forceinline__ float b2f(unsigned short h) {
  unsigned int u = ((unsigned int)h) << 16;
  return __builtin_bit_cast(float, u);
}
__device__ __forceinline__ unsigned short to_bits(float f) { return f2b(f); }
__device__ __forceinline__ unsigned short to_bits(unsigned short u) { return u; }

// async global->LDS, 16B per lane, wave-uniform LDS base (HW adds lane*16)
__device__ __forceinline__ void gl2lds16(const void* g, void* l) {
  __builtin_amdgcn_global_load_lds(
      (const __attribute__((address_space(1))) unsigned int*)g,
      (__attribute__((address_space(3))) unsigned int*)l, 16, 0, 0);
}

// ---------------------------------------------------------------------------
// NT GEMM: C[M,N] = scale * (A @ BT^T) + bias.  A:[M,K] bf16 row-major,
// BT:[N,K] bf16 row-major (i.e. B transposed). 128x128 tile, BK=32, 4 waves.
// T3-minimum 2-phase: double-buffered LDS, prefetch tile t+1 via
// global_load_lds BEFORE computing tile t; one vmcnt(0)+barrier per tile.
// Requires K % 64 == 0 (even number of 32-wide K-tiles).
// ---------------------------------------------------------------------------
template <int OUT_BF16, int HAS_BIAS>
__global__ __launch_bounds__(256, 2) void gemm_bt(
    const unsigned short* __restrict__ A, const unsigned short* __restrict__ BT,
    const float* __restrict__ bias, void* __restrict__ Cv, int M, int N, int K,
    float scale) {
  __shared__ __align__(16) unsigned short sA0[128 * 32];
  __shared__ __align__(16) unsigned short sB0[128 * 32];
  __shared__ __align__(16) unsigned short sA1[128 * 32];
  __shared__ __align__(16) unsigned short sB1[128 * 32];

  const int t = threadIdx.x;
  const int lane = t & 63;
  const int wave = t >> 6;
  const int wr = (wave >> 1) * 64;  // wave row offset in tile
  const int wc = (wave & 1) * 64;   // wave col offset in tile
  const long tileM = (long)blockIdx.y * 128;
  const long tileN = (long)blockIdx.x * 128;

  // staging coords: lane l of wave w covers tile-row 16w + (l>>2),
  // k-chunk (l&3)*8; LDS byte offset = 1024w + 16l (linear, gl2lds-compatible)
  const int sr = t >> 2;       // 0..63
  const int sk = (t & 3) * 8;  // k element offset
  const unsigned short* Ap = A + (tileM + sr) * K + sk;
  const unsigned short* Bp = BT + (tileN + sr) * K + sk;
  const long rowstep = (long)64 * K;
  const int wo = wave * 512;  // wave-uniform LDS element offset

  f32x4 acc[4][4];
#pragma unroll
  for (int m = 0; m < 4; ++m)
#pragma unroll
    for (int n = 0; n < 4; ++n) acc[m][n] = (f32x4)(0.f);

  const int fr = lane & 15;        // fragment row
  const int fk = (lane >> 4) * 8;  // fragment k offset

#define STAGE(sa, sb, k0)                      \
  do {                                         \
    gl2lds16(Ap + (k0), (sa) + wo);            \
    gl2lds16(Ap + rowstep + (k0), (sa) + 2048 + wo); \
    gl2lds16(Bp + (k0), (sb) + wo);            \
    gl2lds16(Bp + rowstep + (k0), (sb) + 2048 + wo); \
  } while (0)

#define COMPUTE(sa, sb)                                                     \
  do {                                                                      \
    bf16x8 fa[4], fb[4];                                                    \
    _Pragma("unroll") for (int m = 0; m < 4; ++m) fa[m] =                   \
        *(const bf16x8*)((sa) + (wr + m * 16 + fr) * 32 + fk);              \
    _Pragma("unroll") for (int n = 0; n < 4; ++n) fb[n] =                   \
        *(const bf16x8*)((sb) + (wc + n * 16 + fr) * 32 + fk);              \
    _Pragma("unroll") for (int m = 0; m < 4; ++m)                           \
        _Pragma("unroll") for (int n = 0; n < 4; ++n) acc[m][n] =           \
            __builtin_amdgcn_mfma_f32_16x16x32_bf16(fa[m], fb[n],           \
                                                    acc[m][n], 0, 0, 0);    \
  } while (0)

  const int nt = K >> 5;  // even by construction
  STAGE(sA0, sB0, 0);
  __syncthreads();  // drain prologue loads
  for (int t2 = 0; t2 < nt; t2 += 2) {
    if (t2 + 1 < nt) STAGE(sA1, sB1, (t2 + 1) << 5);  // prefetch next
    COMPUTE(sA0, sB0);                                // compute current
    __syncthreads();  // vmcnt(0): prefetch landed; lgkm: reads done
    if (t2 + 2 < nt) STAGE(sA0, sB0, (t2 + 2) << 5);
    COMPUTE(sA1, sB1);
    __syncthreads();
  }
#undef STAGE
#undef COMPUTE

  // C/D layout (m89-verified): col = lane&15, row = (lane>>4)*4 + j
  const int cr = (lane >> 4) * 4;
  const int cc = lane & 15;
#pragma unroll
  for (int m = 0; m < 4; ++m) {
#pragma unroll
    for (int n = 0; n < 4; ++n) {
      const long col = tileN + wc + n * 16 + cc;
      const float bv = HAS_BIAS ? bias[col] : 0.f;
#pragma unroll
      for (int j = 0; j < 4; ++j) {
        const long row = tileM + wr + m * 16 + cr + j;
        float v = acc[m][n][j] * scale + bv;
        if (OUT_BF16)
          ((unsigned short*)Cv)[row * N + col] = f2b(v);
        else
          ((float*)Cv)[row * N + col] = v;
      }
    }
  }
}

// ---------------------------------------------------------------------------
// Row softmax over bf16 rows of length 4096, in place. One block per row.
// ---------------------------------------------------------------------------
__global__ __launch_bounds__(256) void softmax_rows(unsigned short* S,
                                                    int ncols) {
  const int t = threadIdx.x;
  const int lane = t & 63;
  const int wave = t >> 6;
  unsigned short* p = S + (long)blockIdx.x * ncols + t * 16;
  uint4 d0 = *(const uint4*)(p);
  uint4 d1 = *(const uint4*)(p + 8);
  unsigned int w[8] = {d0.x, d0.y, d0.z, d0.w, d1.x, d1.y, d1.z, d1.w};
  float v[16];
#pragma unroll
  for (int i = 0; i < 8; ++i) {
    v[2 * i] = b2f((unsigned short)(w[i] & 0xffffu));
    v[2 * i + 1] = b2f((unsigned short)(w[i] >> 16));
  }
  float mx = v[0];
#pragma unroll
  for (int i = 1; i < 16; ++i) mx = fmaxf(mx, v[i]);
#pragma unroll
  for (int off = 32; off > 0; off >>= 1) mx = fmaxf(mx, __shfl_xor(mx, off, 64));
  __shared__ float redm[4], reds[4];
  if (lane == 0) redm[wave] = mx;
  __syncthreads();
  mx = fmaxf(fmaxf(redm[0], redm[1]), fmaxf(redm[2], redm[3]));
  float sum = 0.f;
#pragma unroll
  for (int i = 0; i < 16; ++i) {
    v[i] = __expf(v[i] - mx);
    sum += v[i];
  }
#pragma unroll
  for (int off = 32; off > 0; off >>= 1) sum += __shfl_xor(sum, off, 64);
  if (lane == 0) reds[wave] = sum;
  __syncthreads();
  const float inv = 1.f / (reds[0] + reds[1] + reds[2] + reds[3]);
  unsigned int o[8];
#pragma unroll
  for (int i = 0; i < 8; ++i)
    o[i] = (unsigned int)f2b(v[2 * i] * inv) |
           ((unsigned int)f2b(v[2 * i + 1] * inv) << 16);
  *(uint4*)(p) = make_uint4(o[0], o[1], o[2], o[3]);
  *(uint4*)(p + 8) = make_uint4(o[4], o[5], o[6], o[7]);
}

// ---------------------------------------------------------------------------
// Tiled transpose (+cast to bf16): out[C][R] = in[R][C]. block (32,8), z=batch.
// ---------------------------------------------------------------------------
template <typename TIN>
__global__ void transpose_cast(const TIN* __restrict__ in,
                               unsigned short* __restrict__ out, int R, int C) {
  __shared__ unsigned short tile[32][33];
  const long zoff = (long)blockIdx.z * R * C;
  in += zoff;
  out += zoff;
  const int tx = threadIdx.x, ty = threadIdx.y;
  const int bx = blockIdx.x * 32;  // col base
  const int by = blockIdx.y * 32;  // row base
#pragma unroll
  for (int i = 0; i < 4; ++i)
    tile[ty + i * 8][tx] = to_bits(in[(long)(by + ty + i * 8) * C + bx + tx]);
  __syncthreads();
#pragma unroll
  for (int i = 0; i < 4; ++i)
    out[(long)(bx + ty + i * 8) * R + by + tx] = tile[tx][ty + i * 8];
}

// ---------------------------------------------------------------------------
// Elementwise fp32 -> bf16 cast, vectorized float4 -> 4x bf16.
// ---------------------------------------------------------------------------
__global__ __launch_bounds__(256) void cast_f32_bf16(
    const float* __restrict__ in, unsigned short* __restrict__ out, long n) {
  long i = ((long)blockIdx.x * 256 + threadIdx.x) * 4;
  const long stride = (long)gridDim.x * 256 * 4;
  for (; i < n; i += stride) {
    float4 f = *(const float4*)(&in[i]);
    uint2 o;
    o.x = (unsigned int)f2b(f.x) | ((unsigned int)f2b(f.y) << 16);
    o.y = (unsigned int)f2b(f.z) | ((unsigned int)f2b(f.w) << 16);
    *(uint2*)(&out[i]) = o;
  }
}

extern "C" void kernel_launch(void* const* d_in, const int* in_sizes, int n_in,
                              void* d_out, int out_size, void* d_ws,
                              size_t ws_size, hipStream_t stream) {
  constexpr int Bb = 4, S = 4096, D = 1024;
  constexpr long SD = (long)S * D;
  const float* query = (const float*)d_in[0];
  const float* key_ = (const float*)d_in[1];
  const float* value = (const float*)d_in[2];
  const float* Wh = (const float*)d_in[3];
  const float* bh = (const float*)d_in[4];
  const float* Wk = (const float*)d_in[5];
  const float* bk = (const float*)d_in[6];
  const float* Wv = (const float*)d_in[7];
  const float* bv = (const float*)d_in[8];
  const float* Wo = (const float*)d_in[9];
  const float* bo = (const float*)d_in[10];
  float* out = (float*)d_out;

  char* ws = (char*)d_ws;
  const long MB = 1024 * 1024;
  if (ws_size < (size_t)(232 * MB)) return;  // loud failure: out stays zero
  unsigned short* whT = (unsigned short*)(ws + 0 * MB);
  unsigned short* wkT = (unsigned short*)(ws + 2 * MB);
  unsigned short* wvT = (unsigned short*)(ws + 4 * MB);
  unsigned short* woT = (unsigned short*)(ws + 6 * MB);
  unsigned short* Xb = (unsigned short*)(ws + 8 * MB);    // cast input (32MB)
  unsigned short* q = (unsigned short*)(ws + 40 * MB);    // q proj (32MB)
  unsigned short* Kb = (unsigned short*)(ws + 72 * MB);   // k proj (32MB)
  unsigned short* Vb = (unsigned short*)(ws + 104 * MB);  // v / attn_out (32MB)
  unsigned short* VT = (unsigned short*)(ws + 136 * MB);  // v transposed (32MB)
  unsigned short* Hb = (unsigned short*)(ws + 168 * MB);  // hidden (32MB)
  unsigned short* Sc = (unsigned short*)(ws + 200 * MB);  // scores (32MB)

  dim3 tb32(32, 8);
  transpose_cast<float><<<dim3(32, 32, 1), tb32, 0, stream>>>(Wh, whT, D, D);
  transpose_cast<float><<<dim3(32, 32, 1), tb32, 0, stream>>>(Wk, wkT, D, D);
  transpose_cast<float><<<dim3(32, 32, 1), tb32, 0, stream>>>(Wv, wvT, D, D);
  transpose_cast<float><<<dim3(32, 32, 1), tb32, 0, stream>>>(Wo, woT, D, D);

  const long nX = (long)Bb * SD;
  dim3 gProj(D / 128, Bb * S / 128);  // (8, 128)

  // q = bf16(query) @ Wh + bh
  cast_f32_bf16<<<2048, 256, 0, stream>>>(query, Xb, nX);
  gemm_bt<1, 1><<<gProj, 256, 0, stream>>>(Xb, whT, bh, q, Bb * S, D, D, 1.f);
  // k = (key @ Wh + bh) @ Wk + bk
  cast_f32_bf16<<<2048, 256, 0, stream>>>(key_, Xb, nX);
  gemm_bt<1, 1><<<gProj, 256, 0, stream>>>(Xb, whT, bh, Hb, Bb * S, D, D, 1.f);
  gemm_bt<1, 1><<<gProj, 256, 0, stream>>>(Hb, wkT, bk, Kb, Bb * S, D, D, 1.f);
  // v = (value @ Wh + bh) @ Wv + bv
  cast_f32_bf16<<<2048, 256, 0, stream>>>(value, Xb, nX);
  gemm_bt<1, 1><<<gProj, 256, 0, stream>>>(Xb, whT, bh, Hb, Bb * S, D, D, 1.f);
  gemm_bt<1, 1><<<gProj, 256, 0, stream>>>(Hb, wvT, bv, Vb, Bb * S, D, D, 1.f);

  // VT[b] = v[b]^T  ([D][S])
  transpose_cast<unsigned short>
      <<<dim3(D / 32, S / 32, Bb), tb32, 0, stream>>>(Vb, VT, S, D);

  for (int b = 0; b < Bb; ++b) {
    const unsigned short* qb = q + b * SD;
    const unsigned short* kb = Kb + b * SD;
    const unsigned short* vtb = VT + b * SD;
    unsigned short* ob = Vb + b * SD;  // v no longer needed -> attn_out
    // scores = q @ k^T / 1024
    gemm_bt<1, 0><<<dim3(S / 128, S / 128), 256, 0, stream>>>(
        qb, kb, nullptr, Sc, S, S, D, 1.f / 1024.f);
    softmax_rows<<<S, 256, 0, stream>>>(Sc, S);
    // attn_out = attn @ v   (B^T = VT)
    gemm_bt<1, 0><<<dim3(D / 128, S / 128), 256, 0, stream>>>(
        Sc, vtb, nullptr, ob, S, D, S, 1.f);
  }

  // out = attn_out @ Wo + bo  (fp32 output)
  gemm_bt<0, 1><<<gProj, 256, 0, stream>>>(Vb, woT, bo, out, Bb * S, D, D, 1.f);
}

// Round 5
// 937.138 us; speedup vs baseline: 1.2038x; 1.0914x over previous
//
#include <hip/hip_runtime.h>
#include <stdint.h>

typedef __bf16 bf16x8 __attribute__((ext_vector_type(8)));
typedef float f32x4 __attribute__((ext_vector_type(4)));

__device__ __forceinline__ unsigned short f2b(float f) {
  unsigned int u = __builtin_bit_cast(unsigned int, f);
  u += 0x7fffu + ((u >> 16) & 1u);
  return (unsigned short)(u >> 16);
}
__device__ __forceinline__ float b2f(unsigned short h) {
  unsigned int u = ((unsigned int)h) << 16;
  return __builtin_bit_cast(float, u);
}
__device__ __forceinline__ unsigned short to_bits(float f) { return f2b(f); }
__device__ __forceinline__ unsigned short to_bits(unsigned short u) { return u; }

// async global->LDS, 16B per lane, wave-uniform LDS base (HW adds lane*16)
__device__ __forceinline__ void gl2lds16(const void* g, void* l) {
  __builtin_amdgcn_global_load_lds(
      (const __attribute__((address_space(1))) unsigned int*)g,
      (__attribute__((address_space(3))) unsigned int*)l, 16, 0, 0);
}

#define FENCE asm volatile("" ::: "memory")

// ---------------------------------------------------------------------------
// 8-phase 256x256 NT GEMM (m201-style): C[M,N] = scale*(A @ BT^T) + bias.
// A:[M,K] bf16 row-major, BT:[N,K] bf16 row-major. BK=64, 512 thr (8 waves,
// 2M x 4N), LDS 128KB = [buf][op][khalf][256][32] bf16 planes.
// Swizzle: physical k-block = logical ^ ((row>>1)&3)  (2-way conflicts only).
// Staged via global_load_lds: linear dest, inverse-swizzled per-lane source.
// Schedule: 4 phases per K-tile, quadrant (m-half, k-half); K-half planes die
// after phase 2 -> next-next tile's Kh0 stages into current buffer; counted
// vmcnt(4) once per tile. Requires K % 128 == 0.
// Optional z-batching: per-z strides zA, zB, zC (elements).
// ---------------------------------------------------------------------------
template <int OUT_BF16, int HAS_BIAS>
__global__ __launch_bounds__(512, 2) void gemm_bt8(
    const unsigned short* __restrict__ A, const unsigned short* __restrict__ BT,
    const float* __restrict__ bias, void* __restrict__ Cv, int N, int K,
    float scale, long zA, long zB, long zC) {
  __shared__ __align__(16) unsigned short lds[2][2][2][256][32];  // 128 KiB

  const int t = threadIdx.x;
  const int lane = t & 63;
  const int w = t >> 6;   // wave 0..7
  const int wm = w >> 2;  // 0..1
  const int wn = w & 3;   // 0..3

  // flattened bijective XCD swizzle (all launches have nwg % 8 == 0)
  const int gx = gridDim.x, gy = gridDim.y;
  const int nxy = gx * gy;
  int id = (blockIdx.z * gy + blockIdx.y) * gx + blockIdx.x;
  const int nwg = nxy * gridDim.z;
  id = (id & 7) * (nwg >> 3) + (id >> 3);
  const int bz = id / nxy;
  const int rem = id - bz * nxy;
  const long tileM = (long)(rem / gx) * 256;
  const long tileN = (long)(rem % gx) * 256;

  const unsigned short* Ab = A + (long)bz * zA;
  const unsigned short* Bb = BT + (long)bz * zB;

  // staging: slot s=w*2+j covers LDS rows s*16+(lane>>2); source k-block is
  // inverse-swizzled so that linear LDS write lands swizzled data.
  const int srow = w * 32 + (lane >> 2);
  const int skb = ((lane & 3) ^ ((lane >> 3) & 3)) * 8;
  const unsigned short* Asrc = Ab + (tileM + srow) * K + skb;
  const unsigned short* Bsrc = Bb + (tileN + srow) * K + skb;
  const long jstep = (long)16 * K;

  // stage one (op, khalf) plane of K-tile at offset KT into buffer BUF
#define STG(OP, SRC, BUF, KH, KT)                                           \
  do {                                                                      \
    gl2lds16((SRC) + (KT) + (KH) * 32, &lds[BUF][OP][KH][w * 32][0]);       \
    gl2lds16((SRC) + jstep + (KT) + (KH) * 32,                              \
             &lds[BUF][OP][KH][w * 32 + 16][0]);                            \
  } while (0)

  // fragment read coords (swizzled)
  const int fr = lane & 15;
  const int fsw = ((lane >> 4) ^ ((lane >> 1) & 3)) * 8;

  f32x4 acc[8][4];
#pragma unroll
  for (int m = 0; m < 8; ++m)
#pragma unroll
    for (int n = 0; n < 4; ++n) acc[m][n] = (f32x4)(0.f);

#define PHASE(BUF, MH, KH, STAGES, WAITC)                                   \
  {                                                                         \
    bf16x8 fa[4], fb[4];                                                    \
    _Pragma("unroll") for (int i = 0; i < 4; ++i) fa[i] =                   \
        *(const bf16x8*)&lds[BUF][0][KH][wm * 128 + MH * 64 + i * 16 + fr][fsw]; \
    _Pragma("unroll") for (int i = 0; i < 4; ++i) fb[i] =                   \
        *(const bf16x8*)&lds[BUF][1][KH][wn * 64 + i * 16 + fr][fsw];       \
    STAGES;                                                                 \
    FENCE;                                                                  \
    __builtin_amdgcn_s_barrier();                                           \
    asm volatile("s_waitcnt lgkmcnt(0)" ::: "memory");                      \
    __builtin_amdgcn_s_setprio(1);                                          \
    _Pragma("unroll") for (int i = 0; i < 4; ++i)                           \
        _Pragma("unroll") for (int n = 0; n < 4; ++n) acc[MH * 4 + i][n] =  \
            __builtin_amdgcn_mfma_f32_16x16x32_bf16(fa[i], fb[n],           \
                                                    acc[MH * 4 + i][n], 0,  \
                                                    0, 0);                  \
    __builtin_amdgcn_s_setprio(0);                                          \
    WAITC;                                                                  \
    FENCE;                                                                  \
    __builtin_amdgcn_s_barrier();                                           \
    FENCE;                                                                  \
  }

  const int NT = K >> 6;  // even (K % 128 == 0), >= 2

  // prologue: T0 fully + T1 Kh0; wait T0 (leave T1-Kh0's 4 loads in flight)
  STG(0, Asrc, 0, 0, 0);
  STG(1, Bsrc, 0, 0, 0);
  STG(0, Asrc, 0, 1, 0);
  STG(1, Bsrc, 0, 1, 0);
  STG(0, Asrc, 1, 0, 64);
  STG(1, Bsrc, 1, 0, 64);
  asm volatile("s_waitcnt vmcnt(4)" ::: "memory");
  FENCE;
  __builtin_amdgcn_s_barrier();
  FENCE;

  for (int it = 0; it < NT; it += 2) {
    const int kt1 = (it + 1) << 6;
    const int kt2 = (it + 2) << 6;
    const int kt3 = (it + 3) << 6;
    const bool more = (it + 2) < NT;
    // tile T (buf0)
    PHASE(0, 0, 0, { STG(0, Asrc, 1, 1, kt1); }, {});
    PHASE(0, 1, 0, { STG(1, Bsrc, 1, 1, kt1); }, {});
    PHASE(0, 0, 1, { if (more) STG(0, Asrc, 0, 0, kt2); }, {});
    PHASE(0, 1, 1, { if (more) STG(1, Bsrc, 0, 0, kt2); },
          {
            if (more)
              asm volatile("s_waitcnt vmcnt(4)" ::: "memory");
            else
              asm volatile("s_waitcnt vmcnt(0)" ::: "memory");
          });
    // tile T+1 (buf1)
    PHASE(1, 0, 0, { if (more) STG(0, Asrc, 0, 1, kt2); }, {});
    PHASE(1, 1, 0, { if (more) STG(1, Bsrc, 0, 1, kt2); }, {});
    PHASE(1, 0, 1, { if (more) STG(0, Asrc, 1, 0, kt3); }, {});
    PHASE(1, 1, 1, { if (more) STG(1, Bsrc, 1, 0, kt3); },
          {
            if (more)
              asm volatile("s_waitcnt vmcnt(4)" ::: "memory");
            else
              asm volatile("s_waitcnt vmcnt(0)" ::: "memory");
          });
  }
#undef PHASE
#undef STG

  // epilogue: C/D layout col=lane&15, row=(lane>>4)*4+j (m89-verified)
  const int cr = (lane >> 4) * 4;
  const int cc = lane & 15;
  char* Cb = (char*)Cv;
#pragma unroll
  for (int m = 0; m < 8; ++m) {
#pragma unroll
    for (int n = 0; n < 4; ++n) {
      const long col = tileN + wn * 64 + n * 16 + cc;
      const float bvv = HAS_BIAS ? bias[col] : 0.f;
#pragma unroll
      for (int j = 0; j < 4; ++j) {
        const long row = tileM + wm * 128 + m * 16 + cr + j;
        float v = acc[m][n][j] * scale + bvv;
        if (OUT_BF16)
          ((unsigned short*)Cb)[(long)bz * zC + row * N + col] = f2b(v);
        else
          ((float*)Cb)[(long)bz * zC + row * N + col] = v;
      }
    }
  }
}

// ---------------------------------------------------------------------------
// 2-phase 128x128 NT GEMM (round-4 kernel) — kept for fallback PV path.
// ---------------------------------------------------------------------------
template <int OUT_BF16, int HAS_BIAS>
__global__ __launch_bounds__(256, 2) void gemm_bt(
    const unsigned short* __restrict__ A, const unsigned short* __restrict__ BT,
    const float* __restrict__ bias, void* __restrict__ Cv, int M, int N, int K,
    float scale) {
  __shared__ __align__(16) unsigned short sA0[128 * 32];
  __shared__ __align__(16) unsigned short sB0[128 * 32];
  __shared__ __align__(16) unsigned short sA1[128 * 32];
  __shared__ __align__(16) unsigned short sB1[128 * 32];

  const int t = threadIdx.x;
  const int lane = t & 63;
  const int wave = t >> 6;
  const int wr = (wave >> 1) * 64;
  const int wc = (wave & 1) * 64;
  const long tileM = (long)blockIdx.y * 128;
  const long tileN = (long)blockIdx.x * 128;

  const int sr = t >> 2;
  const int sk = (t & 3) * 8;
  const unsigned short* Ap = A + (tileM + sr) * K + sk;
  const unsigned short* Bp = BT + (tileN + sr) * K + sk;
  const long rowstep = (long)64 * K;
  const int wo = wave * 512;

  f32x4 acc[4][4];
#pragma unroll
  for (int m = 0; m < 4; ++m)
#pragma unroll
    for (int n = 0; n < 4; ++n) acc[m][n] = (f32x4)(0.f);

  const int fr = lane & 15;
  const int fk = (lane >> 4) * 8;

#define STAGE(sa, sb, k0)                            \
  do {                                               \
    gl2lds16(Ap + (k0), (sa) + wo);                  \
    gl2lds16(Ap + rowstep + (k0), (sa) + 2048 + wo); \
    gl2lds16(Bp + (k0), (sb) + wo);                  \
    gl2lds16(Bp + rowstep + (k0), (sb) + 2048 + wo); \
  } while (0)

#define COMPUTE(sa, sb)                                                  \
  do {                                                                   \
    bf16x8 fa[4], fb[4];                                                 \
    _Pragma("unroll") for (int m = 0; m < 4; ++m) fa[m] =                \
        *(const bf16x8*)((sa) + (wr + m * 16 + fr) * 32 + fk);           \
    _Pragma("unroll") for (int n = 0; n < 4; ++n) fb[n] =                \
        *(const bf16x8*)((sb) + (wc + n * 16 + fr) * 32 + fk);           \
    _Pragma("unroll") for (int m = 0; m < 4; ++m)                        \
        _Pragma("unroll") for (int n = 0; n < 4; ++n) acc[m][n] =        \
            __builtin_amdgcn_mfma_f32_16x16x32_bf16(fa[m], fb[n],        \
                                                    acc[m][n], 0, 0, 0); \
  } while (0)

  const int nt = K >> 5;
  STAGE(sA0, sB0, 0);
  __syncthreads();
  for (int t2 = 0; t2 < nt; t2 += 2) {
    if (t2 + 1 < nt) STAGE(sA1, sB1, (t2 + 1) << 5);
    COMPUTE(sA0, sB0);
    __syncthreads();
    if (t2 + 2 < nt) STAGE(sA0, sB0, (t2 + 2) << 5);
    COMPUTE(sA1, sB1);
    __syncthreads();
  }
#undef STAGE
#undef COMPUTE

  const int cr = (lane >> 4) * 4;
  const int cc = lane & 15;
#pragma unroll
  for (int m = 0; m < 4; ++m) {
#pragma unroll
    for (int n = 0; n < 4; ++n) {
      const long col = tileN + wc + n * 16 + cc;
      const float bvv = HAS_BIAS ? bias[col] : 0.f;
#pragma unroll
      for (int j = 0; j < 4; ++j) {
        const long row = tileM + wr + m * 16 + cr + j;
        float v = acc[m][n][j] * scale + bvv;
        if (OUT_BF16)
          ((unsigned short*)Cv)[row * N + col] = f2b(v);
        else
          ((float*)Cv)[row * N + col] = v;
      }
    }
  }
}

// ---------------------------------------------------------------------------
// Row softmax over bf16 rows, in place. One block (256 thr) per row of 4096.
// ---------------------------------------------------------------------------
__global__ __launch_bounds__(256) void softmax_rows(unsigned short* S,
                                                    int ncols) {
  const int t = threadIdx.x;
  const int lane = t & 63;
  const int wave = t >> 6;
  unsigned short* p = S + (long)blockIdx.x * ncols + t * 16;
  uint4 d0 = *(const uint4*)(p);
  uint4 d1 = *(const uint4*)(p + 8);
  unsigned int w[8] = {d0.x, d0.y, d0.z, d0.w, d1.x, d1.y, d1.z, d1.w};
  float v[16];
#pragma unroll
  for (int i = 0; i < 8; ++i) {
    v[2 * i] = b2f((unsigned short)(w[i] & 0xffffu));
    v[2 * i + 1] = b2f((unsigned short)(w[i] >> 16));
  }
  float mx = v[0];
#pragma unroll
  for (int i = 1; i < 16; ++i) mx = fmaxf(mx, v[i]);
#pragma unroll
  for (int off = 32; off > 0; off >>= 1) mx = fmaxf(mx, __shfl_xor(mx, off, 64));
  __shared__ float redm[4], reds[4];
  if (lane == 0) redm[wave] = mx;
  __syncthreads();
  mx = fmaxf(fmaxf(redm[0], redm[1]), fmaxf(redm[2], redm[3]));
  float sum = 0.f;
#pragma unroll
  for (int i = 0; i < 16; ++i) {
    v[i] = __expf(v[i] - mx);
    sum += v[i];
  }
#pragma unroll
  for (int off = 32; off > 0; off >>= 1) sum += __shfl_xor(sum, off, 64);
  if (lane == 0) reds[wave] = sum;
  __syncthreads();
  const float inv = 1.f / (reds[0] + reds[1] + reds[2] + reds[3]);
  unsigned int o[8];
#pragma unroll
  for (int i = 0; i < 8; ++i)
    o[i] = (unsigned int)f2b(v[2 * i] * inv) |
           ((unsigned int)f2b(v[2 * i + 1] * inv) << 16);
  *(uint4*)(p) = make_uint4(o[0], o[1], o[2], o[3]);
  *(uint4*)(p + 8) = make_uint4(o[4], o[5], o[6], o[7]);
}

// ---------------------------------------------------------------------------
// Tiled transpose (+cast to bf16): out[C][R] = in[R][C]. block (32,8), z=batch.
// ---------------------------------------------------------------------------
template <typename TIN>
__global__ void transpose_cast(const TIN* __restrict__ in,
                               unsigned short* __restrict__ out, int R, int C) {
  __shared__ unsigned short tile[32][33];
  const long zoff = (long)blockIdx.z * R * C;
  in += zoff;
  out += zoff;
  const int tx = threadIdx.x, ty = threadIdx.y;
  const int bx = blockIdx.x * 32;
  const int by = blockIdx.y * 32;
#pragma unroll
  for (int i = 0; i < 4; ++i)
    tile[ty + i * 8][tx] = to_bits(in[(long)(by + ty + i * 8) * C + bx + tx]);
  __syncthreads();
#pragma unroll
  for (int i = 0; i < 4; ++i)
    out[(long)(bx + ty + i * 8) * R + by + tx] = tile[tx][ty + i * 8];
}

// ---------------------------------------------------------------------------
// Elementwise fp32 -> bf16 cast, vectorized.
// ---------------------------------------------------------------------------
__global__ __launch_bounds__(256) void cast_f32_bf16(
    const float* __restrict__ in, unsigned short* __restrict__ out, long n) {
  long i = ((long)blockIdx.x * 256 + threadIdx.x) * 4;
  const long stride = (long)gridDim.x * 256 * 4;
  for (; i < n; i += stride) {
    float4 f = *(const float4*)(&in[i]);
    uint2 o;
    o.x = (unsigned int)f2b(f.x) | ((unsigned int)f2b(f.y) << 16);
    o.y = (unsigned int)f2b(f.z) | ((unsigned int)f2b(f.w) << 16);
    *(uint2*)(&out[i]) = o;
  }
}

extern "C" void kernel_launch(void* const* d_in, const int* in_sizes, int n_in,
                              void* d_out, int out_size, void* d_ws,
                              size_t ws_size, hipStream_t stream) {
  constexpr int Bb = 4, S = 4096, D = 1024;
  constexpr long SD = (long)S * D;
  constexpr long SS = (long)S * S;
  const float* query = (const float*)d_in[0];
  const float* key_ = (const float*)d_in[1];
  const float* value = (const float*)d_in[2];
  const float* Wh = (const float*)d_in[3];
  const float* bh = (const float*)d_in[4];
  const float* Wk = (const float*)d_in[5];
  const float* bk = (const float*)d_in[6];
  const float* Wv = (const float*)d_in[7];
  const float* bv = (const float*)d_in[8];
  const float* Wo = (const float*)d_in[9];
  const float* bo = (const float*)d_in[10];
  float* out = (float*)d_out;

  char* ws = (char*)d_ws;
  const long MB = 1024 * 1024;
  if (ws_size < (size_t)(232 * MB)) return;  // loud failure: out stays zero
  const bool batched = ws_size >= (size_t)(328 * MB);
  unsigned short* whT = (unsigned short*)(ws + 0 * MB);
  unsigned short* wkT = (unsigned short*)(ws + 2 * MB);
  unsigned short* wvT = (unsigned short*)(ws + 4 * MB);
  unsigned short* woT = (unsigned short*)(ws + 6 * MB);
  unsigned short* Xb = (unsigned short*)(ws + 8 * MB);    // cast input (32MB)
  unsigned short* q = (unsigned short*)(ws + 40 * MB);    // q proj (32MB)
  unsigned short* Kb = (unsigned short*)(ws + 72 * MB);   // k proj (32MB)
  unsigned short* Vb = (unsigned short*)(ws + 104 * MB);  // v / attn_out (32MB)
  unsigned short* VT = (unsigned short*)(ws + 136 * MB);  // v^T (32MB)
  unsigned short* Hb = (unsigned short*)(ws + 168 * MB);  // hidden (32MB)
  unsigned short* Sc = (unsigned short*)(ws + 200 * MB);  // scores (32 or 128MB)

  dim3 tb32(32, 8);
  transpose_cast<float><<<dim3(32, 32, 1), tb32, 0, stream>>>(Wh, whT, D, D);
  transpose_cast<float><<<dim3(32, 32, 1), tb32, 0, stream>>>(Wk, wkT, D, D);
  transpose_cast<float><<<dim3(32, 32, 1), tb32, 0, stream>>>(Wv, wvT, D, D);
  transpose_cast<float><<<dim3(32, 32, 1), tb32, 0, stream>>>(Wo, woT, D, D);

  const long nX = (long)Bb * SD;
  dim3 gProj(D / 256, Bb * S / 256, 1);  // (4, 64)

  // q = bf16(query) @ Wh + bh
  cast_f32_bf16<<<2048, 256, 0, stream>>>(query, Xb, nX);
  gemm_bt8<1, 1><<<gProj, 512, 0, stream>>>(Xb, whT, bh, q, D, D, 1.f, 0, 0, 0);
  // k = (key @ Wh + bh) @ Wk + bk
  cast_f32_bf16<<<2048, 256, 0, stream>>>(key_, Xb, nX);
  gemm_bt8<1, 1><<<gProj, 512, 0, stream>>>(Xb, whT, bh, Hb, D, D, 1.f, 0, 0, 0);
  gemm_bt8<1, 1><<<gProj, 512, 0, stream>>>(Hb, wkT, bk, Kb, D, D, 1.f, 0, 0, 0);
  // v = (value @ Wh + bh) @ Wv + bv
  cast_f32_bf16<<<2048, 256, 0, stream>>>(value, Xb, nX);
  gemm_bt8<1, 1><<<gProj, 512, 0, stream>>>(Xb, whT, bh, Hb, D, D, 1.f, 0, 0, 0);
  gemm_bt8<1, 1><<<gProj, 512, 0, stream>>>(Hb, wvT, bv, Vb, D, D, 1.f, 0, 0, 0);

  // VT[b] = v[b]^T  ([D][S])
  transpose_cast<unsigned short>
      <<<dim3(D / 32, S / 32, Bb), tb32, 0, stream>>>(Vb, VT, S, D);

  const unsigned short* attn_out;
  if (batched) {
    // scores (all batches) = q @ k^T / 1024
    gemm_bt8<1, 0><<<dim3(S / 256, S / 256, Bb), 512, 0, stream>>>(
        q, Kb, nullptr, Sc, S, D, 1.f / 1024.f, SD, SD, SS);
    softmax_rows<<<Bb * S, 256, 0, stream>>>(Sc, S);
    // attn_out = attn @ v  (reuse q buffer; q dead after scores)
    gemm_bt8<1, 0><<<dim3(D / 256, S / 256, Bb), 512, 0, stream>>>(
        Sc, VT, nullptr, q, D, S, 1.f, SS, SD, SD);
    attn_out = q;
  } else {
    for (int b = 0; b < Bb; ++b) {
      const unsigned short* qb = q + b * SD;
      const unsigned short* kb = Kb + b * SD;
      const unsigned short* vtb = VT + b * SD;
      unsigned short* ob = Vb + b * SD;  // v dead after VT -> attn_out
      gemm_bt8<1, 0><<<dim3(S / 256, S / 256, 1), 512, 0, stream>>>(
          qb, kb, nullptr, Sc, S, D, 1.f / 1024.f, 0, 0, 0);
      softmax_rows<<<S, 256, 0, stream>>>(Sc, S);
      gemm_bt<1, 0><<<dim3(D / 128, S / 128), 256, 0, stream>>>(
          Sc, vtb, nullptr, ob, S, D, S, 1.f);
    }
    attn_out = Vb;
  }

  // out = attn_out @ Wo + bo  (fp32 output)
  gemm_bt8<0, 1><<<gProj, 512, 0, stream>>>(attn_out, woT, bo, out, D, D, 1.f,
                                            0, 0, 0);
}

// Round 6
// 755.416 us; speedup vs baseline: 1.4934x; 1.2406x over previous
//
#include <hip/hip_runtime.h>
#include <stdint.h>

typedef __bf16 bf16x8 __attribute__((ext_vector_type(8)));
typedef float f32x4 __attribute__((ext_vector_type(4)));

__device__ __forceinline__ unsigned short f2b(float f) {
  unsigned int u = __builtin_bit_cast(unsigned int, f);
  u += 0x7fffu + ((u >> 16) & 1u);
  return (unsigned short)(u >> 16);
}
__device__ __forceinline__ float b2f(unsigned short h) {
  unsigned int u = ((unsigned int)h) << 16;
  return __builtin_bit_cast(float, u);
}
__device__ __forceinline__ unsigned short to_bits(float f) { return f2b(f); }
__device__ __forceinline__ unsigned short to_bits(unsigned short u) { return u; }

// async global->LDS, 16B per lane, wave-uniform LDS base (HW adds lane*16)
__device__ __forceinline__ void gl2lds16(const void* g, void* l) {
  __builtin_amdgcn_global_load_lds(
      (const __attribute__((address_space(1))) unsigned int*)g,
      (__attribute__((address_space(3))) unsigned int*)l, 16, 0, 0);
}

#define FENCE asm volatile("" ::: "memory")

// ---------------------------------------------------------------------------
// 8-phase 256x256 NT GEMM (m201-style): C[M,N] = scale*(A @ BT^T) + bias.
// A:[M,K] bf16 row-major, BT:[N,K] bf16 row-major. BK=64, 512 thr (8 waves,
// 2M x 4N), LDS 128KB = [buf][op][khalf][256][32] bf16 planes.
// Swizzle: physical k-block = logical ^ ((row>>1)&3)  (2-way conflicts only).
// Staged via global_load_lds: linear dest, inverse-swizzled per-lane source.
// Schedule: 4 phases per K-tile, quadrant (m-half, k-half); K-half planes die
// after phase 2 -> next-next tile's Kh0 stages into current buffer; counted
// vmcnt(4) once per tile. Requires K % 128 == 0, nwg % 8 == 0.
// Optional z-batching: per-z strides zA, zB, zC (elements).
// ---------------------------------------------------------------------------
template <int OUT_BF16, int HAS_BIAS>
__global__ __launch_bounds__(512, 2) void gemm_bt8(
    const unsigned short* __restrict__ A, const unsigned short* __restrict__ BT,
    const float* __restrict__ bias, void* __restrict__ Cv, int N, int K,
    float scale, long zA, long zB, long zC) {
  __shared__ __align__(16) unsigned short lds[2][2][2][256][32];  // 128 KiB

  const int t = threadIdx.x;
  const int lane = t & 63;
  const int w = t >> 6;   // wave 0..7
  const int wm = w >> 2;  // 0..1
  const int wn = w & 3;   // 0..3

  // flattened bijective XCD swizzle (all launches have nwg % 8 == 0)
  const int gx = gridDim.x, gy = gridDim.y;
  const int nxy = gx * gy;
  int id = (blockIdx.z * gy + blockIdx.y) * gx + blockIdx.x;
  const int nwg = nxy * gridDim.z;
  id = (id & 7) * (nwg >> 3) + (id >> 3);
  const int bz = id / nxy;
  const int rem = id - bz * nxy;
  const long tileM = (long)(rem / gx) * 256;
  const long tileN = (long)(rem % gx) * 256;

  const unsigned short* Ab = A + (long)bz * zA;
  const unsigned short* Bb = BT + (long)bz * zB;

  // staging: slot s=w*2+j covers LDS rows s*16+(lane>>2); source k-block is
  // inverse-swizzled so that linear LDS write lands swizzled data.
  const int srow = w * 32 + (lane >> 2);
  const int skb = ((lane & 3) ^ ((lane >> 3) & 3)) * 8;
  const unsigned short* Asrc = Ab + (tileM + srow) * K + skb;
  const unsigned short* Bsrc = Bb + (tileN + srow) * K + skb;
  const long jstep = (long)16 * K;

  // stage one (op, khalf) plane of K-tile at offset KT into buffer BUF
#define STG(OP, SRC, BUF, KH, KT)                                     \
  do {                                                                \
    gl2lds16((SRC) + (KT) + (KH) * 32, &lds[BUF][OP][KH][w * 32][0]); \
    gl2lds16((SRC) + jstep + (KT) + (KH) * 32,                        \
             &lds[BUF][OP][KH][w * 32 + 16][0]);                      \
  } while (0)

  // fragment read coords (swizzled)
  const int fr = lane & 15;
  const int fsw = ((lane >> 4) ^ ((lane >> 1) & 3)) * 8;

  f32x4 acc[8][4];
#pragma unroll
  for (int m = 0; m < 8; ++m)
#pragma unroll
    for (int n = 0; n < 4; ++n) acc[m][n] = (f32x4)(0.f);

#define PHASE(BUF, MH, KH, STAGES, WAITC)                                   \
  {                                                                         \
    bf16x8 fa[4], fb[4];                                                    \
    _Pragma("unroll") for (int i = 0; i < 4; ++i) fa[i] =                   \
        *(const bf16x8*)&lds[BUF][0][KH][wm * 128 + MH * 64 + i * 16 + fr][fsw]; \
    _Pragma("unroll") for (int i = 0; i < 4; ++i) fb[i] =                   \
        *(const bf16x8*)&lds[BUF][1][KH][wn * 64 + i * 16 + fr][fsw];       \
    STAGES;                                                                 \
    FENCE;                                                                  \
    __builtin_amdgcn_s_barrier();                                           \
    asm volatile("s_waitcnt lgkmcnt(0)" ::: "memory");                      \
    __builtin_amdgcn_s_setprio(1);                                          \
    _Pragma("unroll") for (int i = 0; i < 4; ++i)                           \
        _Pragma("unroll") for (int n = 0; n < 4; ++n) acc[MH * 4 + i][n] =  \
            __builtin_amdgcn_mfma_f32_16x16x32_bf16(fa[i], fb[n],           \
                                                    acc[MH * 4 + i][n], 0,  \
                                                    0, 0);                  \
    __builtin_amdgcn_s_setprio(0);                                          \
    WAITC;                                                                  \
    FENCE;                                                                  \
    __builtin_amdgcn_s_barrier();                                           \
    FENCE;                                                                  \
  }

  const int NT = K >> 6;  // even (K % 128 == 0), >= 2

  // prologue: T0 fully + T1 Kh0; wait T0 (leave T1-Kh0's 4 loads in flight)
  STG(0, Asrc, 0, 0, 0);
  STG(1, Bsrc, 0, 0, 0);
  STG(0, Asrc, 0, 1, 0);
  STG(1, Bsrc, 0, 1, 0);
  STG(0, Asrc, 1, 0, 64);
  STG(1, Bsrc, 1, 0, 64);
  asm volatile("s_waitcnt vmcnt(4)" ::: "memory");
  FENCE;
  __builtin_amdgcn_s_barrier();
  FENCE;

  for (int it = 0; it < NT; it += 2) {
    const int kt1 = (it + 1) << 6;
    const int kt2 = (it + 2) << 6;
    const int kt3 = (it + 3) << 6;
    const bool more = (it + 2) < NT;
    // tile T (buf0)
    PHASE(0, 0, 0, { STG(0, Asrc, 1, 1, kt1); }, {});
    PHASE(0, 1, 0, { STG(1, Bsrc, 1, 1, kt1); }, {});
    PHASE(0, 0, 1, { if (more) STG(0, Asrc, 0, 0, kt2); }, {});
    PHASE(0, 1, 1, { if (more) STG(1, Bsrc, 0, 0, kt2); },
          {
            if (more)
              asm volatile("s_waitcnt vmcnt(4)" ::: "memory");
            else
              asm volatile("s_waitcnt vmcnt(0)" ::: "memory");
          });
    // tile T+1 (buf1)
    PHASE(1, 0, 0, { if (more) STG(0, Asrc, 0, 1, kt2); }, {});
    PHASE(1, 1, 0, { if (more) STG(1, Bsrc, 0, 1, kt2); }, {});
    PHASE(1, 0, 1, { if (more) STG(0, Asrc, 1, 0, kt3); }, {});
    PHASE(1, 1, 1, { if (more) STG(1, Bsrc, 1, 0, kt3); },
          {
            if (more)
              asm volatile("s_waitcnt vmcnt(4)" ::: "memory");
            else
              asm volatile("s_waitcnt vmcnt(0)" ::: "memory");
          });
  }
#undef PHASE
#undef STG

  // epilogue: C/D layout col=lane&15, row=(lane>>4)*4+j (m89-verified)
  const int cr = (lane >> 4) * 4;
  const int cc = lane & 15;
  char* Cb = (char*)Cv;
#pragma unroll
  for (int m = 0; m < 8; ++m) {
#pragma unroll
    for (int n = 0; n < 4; ++n) {
      const long col = tileN + wn * 64 + n * 16 + cc;
      const float bvv = HAS_BIAS ? bias[col] : 0.f;
#pragma unroll
      for (int j = 0; j < 4; ++j) {
        const long row = tileM + wm * 128 + m * 16 + cr + j;
        float v = acc[m][n][j] * scale + bvv;
        if (OUT_BF16)
          ((unsigned short*)Cb)[(long)bz * zC + row * N + col] = f2b(v);
        else
          ((float*)Cb)[(long)bz * zC + row * N + col] = v;
      }
    }
  }
}

// ---------------------------------------------------------------------------
// Fused bias: out[n] = dot(bh, W[:,n]) + badd[n], W given transposed (wT[n][d])
// One wave per output n; blockIdx.y selects {Wk,bk,bhk} vs {Wv,bv,bhv}.
// ---------------------------------------------------------------------------
__global__ __launch_bounds__(64) void fused_bias2(
    const unsigned short* __restrict__ wkT, const unsigned short* __restrict__ wvT,
    const float* __restrict__ bh, const float* __restrict__ bk,
    const float* __restrict__ bv, float* __restrict__ bhk,
    float* __restrict__ bhv) {
  const int n = blockIdx.x;
  const unsigned short* wrow = (blockIdx.y == 0 ? wkT : wvT) + (long)n * 1024;
  const float* badd = blockIdx.y == 0 ? bk : bv;
  float* o = blockIdx.y == 0 ? bhk : bhv;
  const int lane = threadIdx.x;
  float s = 0.f;
#pragma unroll
  for (int i = 0; i < 16; ++i) {
    const int d = lane + i * 64;
    s += bh[d] * b2f(wrow[d]);
  }
#pragma unroll
  for (int off = 32; off > 0; off >>= 1) s += __shfl_xor(s, off, 64);
  if (lane == 0) o[n] = s + badd[n];
}

// ---------------------------------------------------------------------------
// Row softmax over bf16 rows of length 4096, in place. One block per row.
// ---------------------------------------------------------------------------
__global__ __launch_bounds__(256) void softmax_rows(unsigned short* S,
                                                    int ncols) {
  const int t = threadIdx.x;
  const int lane = t & 63;
  const int wave = t >> 6;
  unsigned short* p = S + (long)blockIdx.x * ncols + t * 16;
  uint4 d0 = *(const uint4*)(p);
  uint4 d1 = *(const uint4*)(p + 8);
  unsigned int w[8] = {d0.x, d0.y, d0.z, d0.w, d1.x, d1.y, d1.z, d1.w};
  float v[16];
#pragma unroll
  for (int i = 0; i < 8; ++i) {
    v[2 * i] = b2f((unsigned short)(w[i] & 0xffffu));
    v[2 * i + 1] = b2f((unsigned short)(w[i] >> 16));
  }
  float mx = v[0];
#pragma unroll
  for (int i = 1; i < 16; ++i) mx = fmaxf(mx, v[i]);
#pragma unroll
  for (int off = 32; off > 0; off >>= 1) mx = fmaxf(mx, __shfl_xor(mx, off, 64));
  __shared__ float redm[4], reds[4];
  if (lane == 0) redm[wave] = mx;
  __syncthreads();
  mx = fmaxf(fmaxf(redm[0], redm[1]), fmaxf(redm[2], redm[3]));
  float sum = 0.f;
#pragma unroll
  for (int i = 0; i < 16; ++i) {
    v[i] = __expf(v[i] - mx);
    sum += v[i];
  }
#pragma unroll
  for (int off = 32; off > 0; off >>= 1) sum += __shfl_xor(sum, off, 64);
  if (lane == 0) reds[wave] = sum;
  __syncthreads();
  const float inv = 1.f / (reds[0] + reds[1] + reds[2] + reds[3]);
  unsigned int o[8];
#pragma unroll
  for (int i = 0; i < 8; ++i)
    o[i] = (unsigned int)f2b(v[2 * i] * inv) |
           ((unsigned int)f2b(v[2 * i + 1] * inv) << 16);
  *(uint4*)(p) = make_uint4(o[0], o[1], o[2], o[3]);
  *(uint4*)(p + 8) = make_uint4(o[4], o[5], o[6], o[7]);
}

// ---------------------------------------------------------------------------
// Tiled transpose (+cast to bf16): out[C][R] = in[R][C]. block (32,8), z=batch.
// ---------------------------------------------------------------------------
template <typename TIN>
__global__ void transpose_cast(const TIN* __restrict__ in,
                               unsigned short* __restrict__ out, int R, int C) {
  __shared__ unsigned short tile[32][33];
  const long zoff = (long)blockIdx.z * R * C;
  in += zoff;
  out += zoff;
  const int tx = threadIdx.x, ty = threadIdx.y;
  const int bx = blockIdx.x * 32;
  const int by = blockIdx.y * 32;
#pragma unroll
  for (int i = 0; i < 4; ++i)
    tile[ty + i * 8][tx] = to_bits(in[(long)(by + ty + i * 8) * C + bx + tx]);
  __syncthreads();
#pragma unroll
  for (int i = 0; i < 4; ++i)
    out[(long)(bx + ty + i * 8) * R + by + tx] = tile[tx][ty + i * 8];
}

// ---------------------------------------------------------------------------
// Elementwise fp32 -> bf16 cast, vectorized.
// ---------------------------------------------------------------------------
__global__ __launch_bounds__(256) void cast_f32_bf16(
    const float* __restrict__ in, unsigned short* __restrict__ out, long n) {
  long i = ((long)blockIdx.x * 256 + threadIdx.x) * 4;
  const long stride = (long)gridDim.x * 256 * 4;
  for (; i < n; i += stride) {
    float4 f = *(const float4*)(&in[i]);
    uint2 o;
    o.x = (unsigned int)f2b(f.x) | ((unsigned int)f2b(f.y) << 16);
    o.y = (unsigned int)f2b(f.z) | ((unsigned int)f2b(f.w) << 16);
    *(uint2*)(&out[i]) = o;
  }
}

extern "C" void kernel_launch(void* const* d_in, const int* in_sizes, int n_in,
                              void* d_out, int out_size, void* d_ws,
                              size_t ws_size, hipStream_t stream) {
  constexpr int Bb = 4, S = 4096, D = 1024;
  constexpr long SD = (long)S * D;
  constexpr long SS = (long)S * S;
  constexpr long DD = (long)D * D;
  const float* query = (const float*)d_in[0];
  const float* key_ = (const float*)d_in[1];
  const float* value = (const float*)d_in[2];
  const float* Wh = (const float*)d_in[3];
  const float* bh = (const float*)d_in[4];
  const float* Wk = (const float*)d_in[5];
  const float* bk = (const float*)d_in[6];
  const float* Wv = (const float*)d_in[7];
  const float* bv = (const float*)d_in[8];
  const float* Wo = (const float*)d_in[9];
  const float* bo = (const float*)d_in[10];
  float* out = (float*)d_out;

  char* ws = (char*)d_ws;
  const long MB = 1024 * 1024;
  if (ws_size < (size_t)(232 * MB)) return;  // loud failure: out stays zero
  // persistent through attention:
  unsigned short* whT = (unsigned short*)(ws + 0 * MB);
  unsigned short* wkT = (unsigned short*)(ws + 2 * MB);   // contiguous with wvT
  unsigned short* wvT = (unsigned short*)(ws + 4 * MB);
  unsigned short* woT = (unsigned short*)(ws + 6 * MB);
  unsigned short* q = (unsigned short*)(ws + 8 * MB);     // q / attn_out (32MB)
  unsigned short* Kb = (unsigned short*)(ws + 40 * MB);   // k proj (32MB)
  unsigned short* VT = (unsigned short*)(ws + 72 * MB);   // v^T (32MB)
  unsigned short* Sc = (unsigned short*)(ws + 104 * MB);  // scores ALL (128MB)
  // projection-phase temporaries, aliased INSIDE the Sc region (dead before
  // the scores GEMM overwrites them):
  unsigned short* Xb = (unsigned short*)(ws + 104 * MB);   // cast input (32MB)
  unsigned short* Vb = (unsigned short*)(ws + 136 * MB);   // v proj (32MB)
  unsigned short* WhB = (unsigned short*)(ws + 168 * MB);  // bf16 Wh (2MB)
  unsigned short* FkT = (unsigned short*)(ws + 170 * MB);  // (Wh@Wk)^T (2MB)
  unsigned short* FvT = (unsigned short*)(ws + 172 * MB);  // (Wh@Wv)^T (2MB)
  float* bhk = (float*)(ws + 174 * MB);                    // fused k bias (4KB)
  float* bhv = (float*)(ws + 174 * MB + 4096);             // fused v bias (4KB)

  dim3 tb32(32, 8);
  transpose_cast<float><<<dim3(32, 32, 1), tb32, 0, stream>>>(Wh, whT, D, D);
  transpose_cast<float><<<dim3(32, 32, 1), tb32, 0, stream>>>(Wk, wkT, D, D);
  transpose_cast<float><<<dim3(32, 32, 1), tb32, 0, stream>>>(Wv, wvT, D, D);
  transpose_cast<float><<<dim3(32, 32, 1), tb32, 0, stream>>>(Wo, woT, D, D);

  // fused weights: FkT = (Wh@Wk)^T = wkT @ WhB^T, FvT likewise (z=2 batch;
  // wkT/wvT and FkT/FvT are contiguous with stride DD elements)
  cast_f32_bf16<<<1024, 256, 0, stream>>>(Wh, WhB, DD);
  gemm_bt8<1, 0><<<dim3(D / 256, D / 256, 2), 512, 0, stream>>>(
      wkT, WhB, nullptr, FkT, D, D, 1.f, DD, 0, DD);
  // fused biases: bhk = bh@Wk + bk, bhv = bh@Wv + bv
  fused_bias2<<<dim3(D, 2), 64, 0, stream>>>(wkT, wvT, bh, bk, bv, bhk, bhv);

  const long nX = (long)Bb * SD;
  dim3 gProj(D / 256, Bb * S / 256, 1);  // (4, 64)

  // q = bf16(query) @ Wh + bh
  cast_f32_bf16<<<2048, 256, 0, stream>>>(query, Xb, nX);
  gemm_bt8<1, 1><<<gProj, 512, 0, stream>>>(Xb, whT, bh, q, D, D, 1.f, 0, 0, 0);
  // k = key@(Wh@Wk) + (bh@Wk + bk)
  cast_f32_bf16<<<2048, 256, 0, stream>>>(key_, Xb, nX);
  gemm_bt8<1, 1><<<gProj, 512, 0, stream>>>(Xb, FkT, bhk, Kb, D, D, 1.f, 0, 0, 0);
  // v = value@(Wh@Wv) + (bh@Wv + bv)
  cast_f32_bf16<<<2048, 256, 0, stream>>>(value, Xb, nX);
  gemm_bt8<1, 1><<<gProj, 512, 0, stream>>>(Xb, FvT, bhv, Vb, D, D, 1.f, 0, 0, 0);

  // VT[b] = v[b]^T  ([D][S])
  transpose_cast<unsigned short>
      <<<dim3(D / 32, S / 32, Bb), tb32, 0, stream>>>(Vb, VT, S, D);

  // scores (all batches) = q @ k^T / 1024  — overwrites Xb/Vb/WhB/F*/biases
  gemm_bt8<1, 0><<<dim3(S / 256, S / 256, Bb), 512, 0, stream>>>(
      q, Kb, nullptr, Sc, S, D, 1.f / 1024.f, SD, SD, SS);
  softmax_rows<<<Bb * S, 256, 0, stream>>>(Sc, S);
  // attn_out = attn @ v  (into q; q dead after scores)
  gemm_bt8<1, 0><<<dim3(D / 256, S / 256, Bb), 512, 0, stream>>>(
      Sc, VT, nullptr, q, D, S, 1.f, SS, SD, SD);

  // out = attn_out @ Wo + bo  (fp32 output)
  gemm_bt8<0, 1><<<gProj, 512, 0, stream>>>(q, woT, bo, out, D, D, 1.f, 0, 0, 0);
}